// Round 5
// baseline (280.246 us; speedup 1.0000x reference)
//
#include <hip/hip_runtime.h>
#include <hip/hip_cooperative_groups.h>

namespace cg = cooperative_groups;

// ECE: ece = sum_b | sum_{i in b} (conf_i - acc_i) | / n
// Bin: tt = ceil(c*15), bin b matches tt == b+1 (b in 0..14). Validity free:
// c<=0 -> tt<=0, c>1 -> tt>15, NaN -> 0 -- none match any bin.
//
// Evidence so far: R1 LDS atomics serialize; R2 LDS RMW chains; R3 reg-bins
// 47us; R4 deep unroll lost occupancy (dur ~ 1/occupancy). Replay-warm
// dispatches (hbm_bytes ~1MB) run at IDENTICAL duration to cold ones =>
// NOT HBM-bound; latency/concurrency-structure bound. Bench dur_us carries
// ~100us of non-hist time (2nd launch + 1-block final + gaps).
// R5: single cooperative kernel: hist -> grid.sync -> block 0 final.
// Grid 1024x256 (co-resident by construction; occupancy set by grid, not
// VGPR) + 4-wide interleaved load batch (8 dwordx4 in flight, vmcnt(6)
// before first proc4).

#define NB 15

__device__ __forceinline__ void proc4(float4 c, float4 a, float* __restrict__ bins) {
    float cv[4] = {c.x, c.y, c.z, c.w};
    float av[4] = {a.x, a.y, a.z, a.w};
#pragma unroll
    for (int j = 0; j < 4; ++j) {
        float v = cv[j];
        float d = v - av[j];
        int tt = (int)ceilf(v * 15.0f);   // valid => tt in 1..15
#pragma unroll
        for (int b = 0; b < NB; ++b)
            bins[b] += (tt == b + 1) ? d : 0.0f;   // b+1 inline const
    }
}

__device__ __forceinline__ void hist_body(
        const float* __restrict__ conf, const float* __restrict__ acc,
        float* __restrict__ partials, int n4, int n, int nblocks) {
    float bins[NB];
#pragma unroll
    for (int b = 0; b < NB; ++b) bins[b] = 0.0f;

    const float4* __restrict__ c4 = (const float4*)conf;
    const float4* __restrict__ a4 = (const float4*)acc;
    const int stride = gridDim.x * blockDim.x;
    int i = blockIdx.x * blockDim.x + threadIdx.x;

    // 4-wide: 8 interleaved dwordx4 loads in flight; first proc4 at vmcnt(6)
    for (; i + 3 * stride < n4; i += 4 * stride) {
        float4 c0 = c4[i];
        float4 a0 = a4[i];
        float4 c1 = c4[i + stride];
        float4 a1 = a4[i + stride];
        float4 c2 = c4[i + 2 * stride];
        float4 a2 = a4[i + 2 * stride];
        float4 c3 = c4[i + 3 * stride];
        float4 a3 = a4[i + 3 * stride];
        proc4(c0, a0, bins);
        proc4(c1, a1, bins);
        proc4(c2, a2, bins);
        proc4(c3, a3, bins);
    }
    for (; i < n4; i += stride) proc4(c4[i], a4[i], bins);

    if (blockIdx.x == 0) {              // scalar tail (n % 4)
        for (int k = n4 * 4 + (int)threadIdx.x; k < n; k += blockDim.x) {
            float v = conf[k];
            float d = v - acc[k];
            int tt = (int)ceilf(v * 15.0f);
#pragma unroll
            for (int b = 0; b < NB; ++b)
                bins[b] += (tt == b + 1) ? d : 0.0f;
        }
    }

    // wave reduce (64 lanes)
#pragma unroll
    for (int b = 0; b < NB; ++b) {
        float v = bins[b];
#pragma unroll
        for (int off = 32; off > 0; off >>= 1)
            v += __shfl_down(v, off, 64);
        bins[b] = v;
    }

    __shared__ float wsum[4][NB];
    const int wave = threadIdx.x >> 6;
    const int lane = threadIdx.x & 63;
    if (lane == 0) {
#pragma unroll
        for (int b = 0; b < NB; ++b) wsum[wave][b] = bins[b];
    }
    __syncthreads();
    if (threadIdx.x < NB) {
        float s = wsum[0][threadIdx.x] + wsum[1][threadIdx.x]
                + wsum[2][threadIdx.x] + wsum[3][threadIdx.x];
        partials[threadIdx.x * nblocks + blockIdx.x] = s;
    }
}

__global__ __launch_bounds__(256) void ece_fused(
        const float* __restrict__ conf, const float* __restrict__ acc,
        float* __restrict__ partials, float* __restrict__ out,
        int n4, int n, int nblocks, float inv_n) {
    hist_body(conf, acc, partials, n4, n, nblocks);

    cg::this_grid().sync();             // device-scope fence + grid barrier

    if (blockIdx.x == 0) {
        // threads 0..239: quarter-wave (16 lanes) per bin
        float s = 0.0f;
        const int bin = threadIdx.x >> 4;
        const int sub = threadIdx.x & 15;
        if (threadIdx.x < 240) {
            const float* __restrict__ p = partials + bin * nblocks;
            for (int i = sub; i < nblocks; i += 16) s += p[i];
#pragma unroll
            for (int off = 8; off > 0; off >>= 1)
                s += __shfl_down(s, off, 16);
        }
        __shared__ float bsum[NB];
        if (threadIdx.x < 240 && sub == 0) bsum[bin] = s;
        __syncthreads();
        if (threadIdx.x == 0) {
            float t = 0.0f;
#pragma unroll
            for (int b = 0; b < NB; ++b) t += fabsf(bsum[b]);
            out[0] = t * inv_n;
        }
    }
}

// ---- fallback path (two plain launches) if cooperative capture fails ----
__global__ __launch_bounds__(256) void ece_hist(
        const float* __restrict__ conf, const float* __restrict__ acc,
        float* __restrict__ partials, int n4, int n, int nblocks) {
    hist_body(conf, acc, partials, n4, n, nblocks);
}

__global__ __launch_bounds__(960) void ece_final(
        const float* __restrict__ partials, float* __restrict__ out,
        int nblocks, float inv_n) {
    __shared__ float bsum[NB];
    const int wave = threadIdx.x >> 6;
    const int lane = threadIdx.x & 63;
    float s = 0.0f;
    for (int i = lane; i < nblocks; i += 64)
        s += partials[wave * nblocks + i];
#pragma unroll
    for (int off = 32; off > 0; off >>= 1)
        s += __shfl_down(s, off, 64);
    if (lane == 0) bsum[wave] = s;
    __syncthreads();
    if (threadIdx.x == 0) {
        float t = 0.0f;
#pragma unroll
        for (int b = 0; b < NB; ++b) t += fabsf(bsum[b]);
        out[0] = t * inv_n;
    }
}

extern "C" void kernel_launch(void* const* d_in, const int* in_sizes, int n_in,
                              void* d_out, int out_size, void* d_ws, size_t ws_size,
                              hipStream_t stream) {
    const float* conf = (const float*)d_in[0];
    const float* acc  = (const float*)d_in[1];
    float* partials   = (float*)d_ws;
    float* out        = (float*)d_out;

    const int n  = in_sizes[0];
    const int n4 = n / 4;
    const float inv_n = 1.0f / (float)n;

    int nblocks = 1024;   // 4 blocks/CU -> co-resident at any VGPR<=128
    while ((size_t)NB * nblocks * sizeof(float) > ws_size && nblocks > 1)
        nblocks >>= 1;
    int max_grid = (n4 + 255) / 256;
    if (nblocks > max_grid) nblocks = max_grid;
    if (nblocks < 1) nblocks = 1;

    int n4_ = n4, n_ = n, nb_ = nblocks;
    float invn_ = inv_n;
    const float* conf_ = conf;
    const float* acc_  = acc;
    float* part_ = partials;
    float* out_  = out;
    void* args[] = {&conf_, &acc_, &part_, &out_, &n4_, &n_, &nb_, &invn_};

    hipError_t e = hipLaunchCooperativeKernel((const void*)ece_fused,
                                              dim3(nblocks), dim3(256),
                                              args, 0, stream);
    if (e != hipSuccess) {
        (void)hipGetLastError();   // clear sticky error, take two-launch path
        ece_hist<<<nblocks, 256, 0, stream>>>(conf, acc, partials, n4, n, nblocks);
        ece_final<<<1, 960, 0, stream>>>(partials, out, nblocks, inv_n);
    }
}

// Round 6
// 167.224 us; speedup vs baseline: 1.6759x; 1.6759x over previous
//
#include <hip/hip_runtime.h>

// ECE: ece = sum_b | sum_{i in b} (conf_i - acc_i) | / n
// Bin: tt = ceil(c*15), bin b matches tt == b+1 (b in 0..14). Validity free:
// c<=0 -> tt<=0, c>1 -> tt>15, NaN -> 0 -- none match any bin.
//
// Ladder: R1 LDS atomics serialize (~210cyc). R2 LDS RMW chains (47us).
// R3 reg-bins grid-stride (48us, VALU 36%). R4 deep unroll lost occupancy.
// R5 grid.sync costs ~100us -> two launches it is.
// Invariant: warm-replay == cold duration => not HBM/latency-tier bound.
// R6 theory: grid-stride with 8MB per-wave hops thrashes TLB / kills
// sequential streaming. Switch to block-contiguous chunks: each block owns
// a contiguous 128KB region, threads sweep at stride 256 (coalesced 1KB
// wave-lines, sequential 4KB advance, 1-2 pages per block). Register bins,
// 4-deep load batch (8 dwordx4 in flight), launch_bounds(256,8).

#define NB 15

__device__ __forceinline__ void proc4(float4 c, float4 a, float* __restrict__ bins) {
    float cv[4] = {c.x, c.y, c.z, c.w};
    float av[4] = {a.x, a.y, a.z, a.w};
#pragma unroll
    for (int j = 0; j < 4; ++j) {
        float v = cv[j];
        float d = v - av[j];
        int tt = (int)ceilf(v * 15.0f);   // valid => tt in 1..15
#pragma unroll
        for (int b = 0; b < NB; ++b)
            bins[b] += (tt == b + 1) ? d : 0.0f;   // b+1 inline const
    }
}

__global__ __launch_bounds__(256, 8) void ece_hist(
        const float* __restrict__ conf,
        const float* __restrict__ acc,
        float* __restrict__ partials,   // layout [NB][nblocks]
        int n4, int n, int nblocks, int chunk4) {
    float bins[NB];
#pragma unroll
    for (int b = 0; b < NB; ++b) bins[b] = 0.0f;

    const float4* __restrict__ c4 = (const float4*)conf;
    const float4* __restrict__ a4 = (const float4*)acc;

    const int base = blockIdx.x * chunk4;           // contiguous block chunk
    const int end  = min(base + chunk4, n4);
    int i = base + (int)threadIdx.x;

    // 4-deep: 8 dwordx4 loads in flight; wave advances 4KB per step,
    // all within the block's contiguous region.
    for (; i + 768 < end; i += 1024) {
        float4 c0 = c4[i];
        float4 a0 = a4[i];
        float4 c1 = c4[i + 256];
        float4 a1 = a4[i + 256];
        float4 c2 = c4[i + 512];
        float4 a2 = a4[i + 512];
        float4 c3 = c4[i + 768];
        float4 a3 = a4[i + 768];
        proc4(c0, a0, bins);
        proc4(c1, a1, bins);
        proc4(c2, a2, bins);
        proc4(c3, a3, bins);
    }
    for (; i < end; i += 256) proc4(c4[i], a4[i], bins);

    // scalar tail (n % 4) — block 0 only (empty when n is a multiple of 4)
    if (blockIdx.x == 0) {
        for (int k = n4 * 4 + (int)threadIdx.x; k < n; k += blockDim.x) {
            float v = conf[k];
            float d = v - acc[k];
            int tt = (int)ceilf(v * 15.0f);
#pragma unroll
            for (int b = 0; b < NB; ++b)
                bins[b] += (tt == b + 1) ? d : 0.0f;
        }
    }

    // wave reduction (64 lanes)
#pragma unroll
    for (int b = 0; b < NB; ++b) {
        float v = bins[b];
#pragma unroll
        for (int off = 32; off > 0; off >>= 1)
            v += __shfl_down(v, off, 64);
        bins[b] = v;
    }

    __shared__ float wsum[4][NB];       // 256 threads = 4 waves
    const int wave = threadIdx.x >> 6;
    const int lane = threadIdx.x & 63;
    if (lane == 0) {
#pragma unroll
        for (int b = 0; b < NB; ++b) wsum[wave][b] = bins[b];
    }
    __syncthreads();

    if (threadIdx.x < NB) {
        float s = wsum[0][threadIdx.x] + wsum[1][threadIdx.x]
                + wsum[2][threadIdx.x] + wsum[3][threadIdx.x];
        partials[threadIdx.x * nblocks + blockIdx.x] = s;   // no atomics
    }
}

__global__ __launch_bounds__(960) void ece_final(
        const float* __restrict__ partials,  // [NB][nblocks]
        float* __restrict__ out, int nblocks, float inv_n) {
    __shared__ float bsum[NB];
    const int wave = threadIdx.x >> 6;   // 15 waves, one per bin
    const int lane = threadIdx.x & 63;

    float s = 0.0f;
    for (int i = lane; i < nblocks; i += 64)
        s += partials[wave * nblocks + i];   // coalesced per wave
#pragma unroll
    for (int off = 32; off > 0; off >>= 1)
        s += __shfl_down(s, off, 64);
    if (lane == 0) bsum[wave] = s;
    __syncthreads();

    if (threadIdx.x == 0) {
        float t = 0.0f;
#pragma unroll
        for (int b = 0; b < NB; ++b) t += fabsf(bsum[b]);
        out[0] = t * inv_n;
    }
}

extern "C" void kernel_launch(void* const* d_in, const int* in_sizes, int n_in,
                              void* d_out, int out_size, void* d_ws, size_t ws_size,
                              hipStream_t stream) {
    const float* conf = (const float*)d_in[0];
    const float* acc  = (const float*)d_in[1];
    float* partials   = (float*)d_ws;
    float* out        = (float*)d_out;

    const int n  = in_sizes[0];
    const int n4 = n / 4;

    int nblocks = 2048;                          // 8 blocks/CU
    while ((size_t)NB * nblocks * sizeof(float) > ws_size && nblocks > 1)
        nblocks >>= 1;
    int max_grid = (n4 + 255) / 256;
    if (nblocks > max_grid) nblocks = max_grid;
    if (nblocks < 1) nblocks = 1;

    // contiguous chunk per block, multiple of 256 float4s
    int chunk4 = (n4 + nblocks - 1) / nblocks;
    chunk4 = (chunk4 + 255) & ~255;

    ece_hist<<<nblocks, 256, 0, stream>>>(conf, acc, partials, n4, n, nblocks,
                                          chunk4);
    ece_final<<<1, 960, 0, stream>>>(partials, out, nblocks, 1.0f / (float)n);
}

// Round 7
// 158.128 us; speedup vs baseline: 1.7723x; 1.0575x over previous
//
#include <hip/hip_runtime.h>

// ECE: ece = sum_b | sum_{i in b} (conf_i - acc_i) | / n
// Bin: tt = ceil(c*15), bin b matches tt == b+1. Validity free: c<=0 -> tt<=0,
// c>1 -> tt>15, NaN -> 0 -- none match any bin.
//
// Ladder: R1 LDS atomics ~210cyc serial. R2 LDS RMW chains 47us. R3 reg-bins
// 48us (VGPR 32, ~2 loads in flight). R4 deep batch VGPR 60 but 8MB-scattered
// -> 68us. R5 grid.sync +100us. R6 contiguous, compiler re-collapsed to VGPR
// 32 -> 56us. m13 copy proves 6.3 TB/s streaming is possible -> limiter is the
// load->consume scheduling, not the memory system.
// R7: take the register allocator out of the loop: global_load_lds (width=16)
// into wave-private triple-buffered LDS tiles, explicit counted vmcnt (never 0
// in steady state) + sched_barrier fences, 2 tiles in flight per wave.
// Staging uses ZERO data VGPRs -- nothing for the compiler to serialize.
// No __syncthreads in the pipeline (wave-private buffers).

#define NB 15
#define NWAVE 4     // waves per block
#define NBUF 3      // triple buffer: stage j+2 never targets the buf being read
#define TF4 64      // float4s per tile per array (256 floats = 1 KB)

__device__ __forceinline__ void proc4(float4 c, float4 a, float* __restrict__ bins) {
    float cv[4] = {c.x, c.y, c.z, c.w};
    float av[4] = {a.x, a.y, a.z, a.w};
#pragma unroll
    for (int j = 0; j < 4; ++j) {
        float v = cv[j];
        float d = v - av[j];
        int tt = (int)ceilf(v * 15.0f);   // valid => tt in 1..15
#pragma unroll
        for (int b = 0; b < NB; ++b)
            bins[b] += (tt == b + 1) ? d : 0.0f;   // b+1 inline const
    }
}

__global__ __launch_bounds__(256, 6) void ece_hist(
        const float* __restrict__ conf,
        const float* __restrict__ acc,
        float* __restrict__ partials,   // layout [NB][nblocks]
        int n4, int n, int nblocks) {
    __shared__ float ldsC[NWAVE][NBUF][TF4 * 4];   // 12 KB
    __shared__ float ldsA[NWAVE][NBUF][TF4 * 4];   // 12 KB  -> 24 KB/block

    float bins[NB];
#pragma unroll
    for (int b = 0; b < NB; ++b) bins[b] = 0.0f;

    const int wave = threadIdx.x >> 6;
    const int lane = threadIdx.x & 63;

    const int ntiles = n4 >> 6;                      // full 64-float4 tiles
    const int per = ntiles / nblocks, rem = ntiles % nblocks;
    const int tstart = blockIdx.x * per + min(blockIdx.x, rem);
    const int tcnt   = per + (blockIdx.x < rem ? 1 : 0);
    // this wave's tiles: tstart + wave + NWAVE*j, j in [0, J)
    const int J = (tcnt > wave) ? ((tcnt - 1 - wave) / NWAVE + 1) : 0;

#define TILE_OF(j) ((long)(tstart + wave + NWAVE * (j)))
#define STAGE(j) do {                                                         \
        long base_ = TILE_OF(j) * (TF4 * 4) + lane * 4;                       \
        __builtin_amdgcn_global_load_lds(                                     \
            (const __attribute__((address_space(1))) void*)(conf + base_),    \
            (__attribute__((address_space(3))) void*)&ldsC[wave][(j) % NBUF][0],\
            16, 0, 0);                                                        \
        __builtin_amdgcn_global_load_lds(                                     \
            (const __attribute__((address_space(1))) void*)(acc + base_),     \
            (__attribute__((address_space(3))) void*)&ldsA[wave][(j) % NBUF][0],\
            16, 0, 0);                                                        \
    } while (0)

    if (J > 0) STAGE(0);
    if (J > 1) STAGE(1);

    for (int j = 0; j < J; ++j) {
        if (j + 2 < J) STAGE(j + 2);            // 2-ahead, into a free buffer
        __builtin_amdgcn_sched_barrier(0);      // pin stage BEFORE the wait
        const int ahead = J - 1 - j;            // staged tiles after j
        if (ahead >= 2)      asm volatile("s_waitcnt vmcnt(4)" ::: "memory");
        else if (ahead == 1) asm volatile("s_waitcnt vmcnt(2)" ::: "memory");
        else                 asm volatile("s_waitcnt vmcnt(0)" ::: "memory");
        __builtin_amdgcn_sched_barrier(0);      // nothing hoists above the wait
        float4 c = *(const float4*)&ldsC[wave][j % NBUF][lane * 4];
        float4 a = *(const float4*)&ldsA[wave][j % NBUF][lane * 4];
        proc4(c, a, bins);
    }

    // leftovers: partial tile (n4 % 64 float4s) + scalar tail (n % 4) — block 0
    if (blockIdx.x == 0) {
        for (int i4 = ntiles * TF4 + (int)threadIdx.x; i4 < n4; i4 += 256) {
            float4 c = ((const float4*)conf)[i4];
            float4 a = ((const float4*)acc)[i4];
            proc4(c, a, bins);
        }
        for (int k = n4 * 4 + (int)threadIdx.x; k < n; k += 256) {
            float v = conf[k];
            float d = v - acc[k];
            int tt = (int)ceilf(v * 15.0f);
#pragma unroll
            for (int b = 0; b < NB; ++b)
                bins[b] += (tt == b + 1) ? d : 0.0f;
        }
    }

    // wave reduction (64 lanes)
#pragma unroll
    for (int b = 0; b < NB; ++b) {
        float v = bins[b];
#pragma unroll
        for (int off = 32; off > 0; off >>= 1)
            v += __shfl_down(v, off, 64);
        bins[b] = v;
    }

    __shared__ float wsum[NWAVE][NB];
    if (lane == 0) {
#pragma unroll
        for (int b = 0; b < NB; ++b) wsum[wave][b] = bins[b];
    }
    __syncthreads();

    if (threadIdx.x < NB) {
        float s = wsum[0][threadIdx.x] + wsum[1][threadIdx.x]
                + wsum[2][threadIdx.x] + wsum[3][threadIdx.x];
        partials[threadIdx.x * nblocks + blockIdx.x] = s;   // no atomics
    }
}

__global__ __launch_bounds__(960) void ece_final(
        const float* __restrict__ partials,  // [NB][nblocks]
        float* __restrict__ out, int nblocks, float inv_n) {
    __shared__ float bsum[NB];
    const int wave = threadIdx.x >> 6;   // 15 waves, one per bin
    const int lane = threadIdx.x & 63;

    float s = 0.0f;
    for (int i = lane; i < nblocks; i += 64)
        s += partials[wave * nblocks + i];   // coalesced per wave
#pragma unroll
    for (int off = 32; off > 0; off >>= 1)
        s += __shfl_down(s, off, 64);
    if (lane == 0) bsum[wave] = s;
    __syncthreads();

    if (threadIdx.x == 0) {
        float t = 0.0f;
#pragma unroll
        for (int b = 0; b < NB; ++b) t += fabsf(bsum[b]);
        out[0] = t * inv_n;
    }
}

extern "C" void kernel_launch(void* const* d_in, const int* in_sizes, int n_in,
                              void* d_out, int out_size, void* d_ws, size_t ws_size,
                              hipStream_t stream) {
    const float* conf = (const float*)d_in[0];
    const float* acc  = (const float*)d_in[1];
    float* partials   = (float*)d_ws;
    float* out        = (float*)d_out;

    const int n  = in_sizes[0];
    const int n4 = n / 4;

    int nblocks = 1536;                      // 6 blocks/CU (24 KB LDS each)
    while ((size_t)NB * nblocks * sizeof(float) > ws_size && nblocks > 1)
        nblocks >>= 1;
    int max_grid = (n4 + 255) / 256;
    if (nblocks > max_grid) nblocks = max_grid;
    if (nblocks < 1) nblocks = 1;

    ece_hist<<<nblocks, 256, 0, stream>>>(conf, acc, partials, n4, n, nblocks);
    ece_final<<<1, 960, 0, stream>>>(partials, out, nblocks, 1.0f / (float)n);
}